// Round 4
// baseline (30.814 us; speedup 1.0000x reference)
//
#include <hip/hip_runtime.h>
#include <math.h>

namespace {
constexpr int Nn = 4, Hh = 256, Ww = 256;
constexpr int HW = Hh * Ww;
constexpr int P  = Nn * HW;          // 262144 pixels
constexpr float ZFAR  = 100.0f;
constexpr float ZNEAR = 1.0f;
constexpr float INV_SIG = 1.0f / (1e-4f + 1e-8f);   // 1/(SIGMA+1e-8)
constexpr float INV_GAM = 1.0f / 1e-4f;             // 1/GAMMA
constexpr float EPSF    = 1e-10f;
constexpr float INV_ZR  = 1.0f / (ZFAR - ZNEAR);
}

// 4 lanes per pixel; lane c owns channels [4c, 4c+4)
__global__ __launch_bounds__(256) void render_kernel(
    const float* __restrict__ vf,     // (V,16)
    const float* __restrict__ bary,   // (P,8,3)
    const float* __restrict__ dists,  // (P,8)
    const float* __restrict__ zbuf,   // (P,8)
    const int*  __restrict__ faces,   // (F,3)
    const int*  __restrict__ p2f,     // (P,8)
    float* __restrict__ out)          // (N,17,H,W)
{
    const int t = blockIdx.x * blockDim.x + threadIdx.x;
    const int p = t >> 2;             // pixel
    const int c = t & 3;              // channel quad

    // ---- streaming loads (quad-identical addresses -> broadcast-merged) ----
    const int4* fp = reinterpret_cast<const int4*>(p2f + (size_t)p * 8);
    int4 fa = fp[0], fb = fp[1];
    int fk[8] = {fa.x, fa.y, fa.z, fa.w, fb.x, fb.y, fb.z, fb.w};

    const float4* zp = reinterpret_cast<const float4*>(zbuf + (size_t)p * 8);
    float4 za = zp[0], zb = zp[1];

    const float4* dp = reinterpret_cast<const float4*>(dists + (size_t)p * 8);
    float4 da = dp[0], db = dp[1];
    float dk[8] = {da.x, da.y, da.z, da.w, db.x, db.y, db.z, db.w};

    float zraw[8] = {za.x, za.y, za.z, za.w, zb.x, zb.y, zb.z, zb.w};
    float zi[8];
    float zmax = EPSF;
#pragma unroll
    for (int k = 0; k < 8; ++k) {
        const bool valid = fk[k] >= 0;
        float zv = valid ? (ZFAR - zraw[k]) * INV_ZR : 0.0f;
        zi[k] = zv;
        zmax = fmaxf(zmax, zv);
    }

    const float delta = fmaxf(__expf((EPSF - zmax) * INV_GAM), EPSF);
    float denom = delta;
    float keep  = 1.0f;

    float4 acc = make_float4(0.f, 0.f, 0.f, 0.f);

    const float* bpx = bary + (size_t)p * 24;

#pragma unroll
    for (int k = 0; k < 8; ++k) {
        const bool valid = fk[k] >= 0;
        float pr = valid ? 1.0f / (1.0f + __expf(dk[k] * INV_SIG)) : 0.0f;
        keep *= (1.0f - pr);
        float wv = pr * __expf((zi[k] - zmax) * INV_GAM);
        denom += wv;
        if (wv > 0.0f) {
            const int f = fk[k];
            // one 16B load covers v0,v1,v2 (+4B slack, page-safe)
            const int4 vidx = *reinterpret_cast<const int4*>(faces + (size_t)f * 3);
            // one 16B load covers the 3 bary coords (+4B slack, page-safe)
            const float4 bq = *reinterpret_cast<const float4*>(bpx + k * 3);
            const float c0 = wv * bq.x;
            const float c1 = wv * bq.y;
            const float c2 = wv * bq.z;
            // each lane reads its 16B chunk of each 64B vertex row;
            // the quad's 4 chunks merge into one line-request per row
            const float4 r0 = *(reinterpret_cast<const float4*>(vf + (size_t)vidx.x * 16) + c);
            const float4 r1 = *(reinterpret_cast<const float4*>(vf + (size_t)vidx.y * 16) + c);
            const float4 r2 = *(reinterpret_cast<const float4*>(vf + (size_t)vidx.z * 16) + c);
            acc.x = fmaf(c0, r0.x, acc.x); acc.y = fmaf(c0, r0.y, acc.y);
            acc.z = fmaf(c0, r0.z, acc.z); acc.w = fmaf(c0, r0.w, acc.w);
            acc.x = fmaf(c1, r1.x, acc.x); acc.y = fmaf(c1, r1.y, acc.y);
            acc.z = fmaf(c1, r1.z, acc.z); acc.w = fmaf(c1, r1.w, acc.w);
            acc.x = fmaf(c2, r2.x, acc.x); acc.y = fmaf(c2, r2.y, acc.y);
            acc.z = fmaf(c2, r2.z, acc.z); acc.w = fmaf(c2, r2.w, acc.w);
        }
    }

    // ---- epilogue ----
    const float invden = 1.0f / denom;
    const int n  = p >> 16;           // p / HW  (HW = 65536)
    const int hw = p & (HW - 1);
    float* o = out + (size_t)n * 17 * HW + hw;
    const int cb = c * 4;
    o[(size_t)(cb + 0) * HW] = acc.x * invden;
    o[(size_t)(cb + 1) * HW] = acc.y * invden;
    o[(size_t)(cb + 2) * HW] = acc.z * invden;
    o[(size_t)(cb + 3) * HW] = acc.w * invden;
    if (c == 0) o[(size_t)16 * HW] = 1.0f - keep;   // alpha
}

extern "C" void kernel_launch(void* const* d_in, const int* in_sizes, int n_in,
                              void* d_out, int out_size, void* d_ws, size_t ws_size,
                              hipStream_t stream) {
    const float* vf    = (const float*)d_in[0];
    const float* bary  = (const float*)d_in[1];
    const float* dists = (const float*)d_in[2];
    const float* zbuf  = (const float*)d_in[3];
    const int*   faces = (const int*)d_in[4];
    const int*   p2f   = (const int*)d_in[5];
    float* out = (float*)d_out;

    render_kernel<<<dim3((P * 4) / 256), dim3(256), 0, stream>>>(
        vf, bary, dists, zbuf, faces, p2f, out);
}

// Round 5
// 23.681 us; speedup vs baseline: 1.3012x; 1.3012x over previous
//
#include <hip/hip_runtime.h>
#include <math.h>

namespace {
constexpr int Nn = 4, Hh = 256, Ww = 256;
constexpr int HW = Hh * Ww;
constexpr int P  = Nn * HW;          // 262144 pixels
constexpr float ZFAR  = 100.0f;
constexpr float ZNEAR = 1.0f;
constexpr float INV_SIG = 1.0f / (1e-4f + 1e-8f);   // 1/(SIGMA+1e-8)
constexpr float INV_GAM = 1.0f / 1e-4f;             // 1/GAMMA
constexpr float EPSF    = 1e-10f;
constexpr float INV_ZR  = 1.0f / (ZFAR - ZNEAR);
}

#define FMA4(A, C, Rp, i)                                   \
    {                                                       \
        float4 _t = (Rp)[i];                                \
        A.x = fmaf((C), _t.x, A.x);                         \
        A.y = fmaf((C), _t.y, A.y);                         \
        A.z = fmaf((C), _t.z, A.z);                         \
        A.w = fmaf((C), _t.w, A.w);                         \
    }

__global__ __launch_bounds__(256) void render_kernel(
    const float* __restrict__ vf,     // (V,16)
    const float* __restrict__ bary,   // (P,8,3)
    const float* __restrict__ dists,  // (P,8)
    const float* __restrict__ zbuf,   // (P,8)
    const int*  __restrict__ faces,   // (F,3)
    const int*  __restrict__ p2f,     // (P,8)
    float* __restrict__ out)          // (N,17,H,W)
{
    const int p = blockIdx.x * blockDim.x + threadIdx.x;
    if (p >= P) return;

    // ---- all streaming loads issued upfront (independent -> max MLP) ----
    const int4*   fp = reinterpret_cast<const int4*>(p2f + (size_t)p * 8);
    const float4* zp = reinterpret_cast<const float4*>(zbuf + (size_t)p * 8);
    const float4* dp = reinterpret_cast<const float4*>(dists + (size_t)p * 8);
    const float4* bp = reinterpret_cast<const float4*>(bary + (size_t)p * 24);
    int4   fA = fp[0], fB = fp[1];
    float4 zA = zp[0], zB = zp[1];
    float4 dA = dp[0], dB = dp[1];
    float4 b0 = bp[0], b1 = bp[1], b2 = bp[2], b3 = bp[3], b4 = bp[4], b5 = bp[5];

    int fk[8] = {fA.x, fA.y, fA.z, fA.w, fB.x, fB.y, fB.z, fB.w};
    float zraw[8] = {zA.x, zA.y, zA.z, zA.w, zB.x, zB.y, zB.z, zB.w};
    float dk[8] = {dA.x, dA.y, dA.z, dA.w, dB.x, dB.y, dB.z, dB.w};
    float bc[24] = {b0.x, b0.y, b0.z, b0.w,
                    b1.x, b1.y, b1.z, b1.w,
                    b2.x, b2.y, b2.z, b2.w,
                    b3.x, b3.y, b3.z, b3.w,
                    b4.x, b4.y, b4.z, b4.w,
                    b5.x, b5.y, b5.z, b5.w};

    // ---- pass 1: z_inv and max ----
    float zi[8];
    float zmax = EPSF;
#pragma unroll
    for (int k = 0; k < 8; ++k) {
        const bool valid = fk[k] >= 0;
        float zv = valid ? (ZFAR - zraw[k]) * INV_ZR : 0.0f;
        zi[k] = zv;
        zmax = fmaxf(zmax, zv);
    }

    // ---- pass 2: weights, denom, alpha ----
    const float delta = fmaxf(__expf((EPSF - zmax) * INV_GAM), EPSF);
    float denom = delta;
    float keep  = 1.0f;
    float wv[8];
#pragma unroll
    for (int k = 0; k < 8; ++k) {
        const bool valid = fk[k] >= 0;
        float pr = valid ? 1.0f / (1.0f + __expf(dk[k] * INV_SIG)) : 0.0f;
        keep *= (1.0f - pr);
        float w = pr * __expf((zi[k] - zmax) * INV_GAM);
        wv[k] = w;
        denom += w;
    }

    // ---- iterative dense argmax gather: ~2 wave-uniform iterations ----
    float4 acc0 = make_float4(0.f, 0.f, 0.f, 0.f);
    float4 acc1 = make_float4(0.f, 0.f, 0.f, 0.f);
    float4 acc2 = make_float4(0.f, 0.f, 0.f, 0.f);
    float4 acc3 = make_float4(0.f, 0.f, 0.f, 0.f);

    while (true) {
        // unrolled cndmask-chain argmax (all compile-time indices)
        float wb = 0.0f, s0 = 0.0f, s1 = 0.0f, s2 = 0.0f;
        int fsel = 0, ksel = -1;
#pragma unroll
        for (int k = 0; k < 8; ++k) {
            const bool better = wv[k] > wb;
            wb   = better ? wv[k] : wb;
            fsel = better ? fk[k] : fsel;
            ksel = better ? k : ksel;
            s0   = better ? bc[k * 3 + 0] : s0;
            s1   = better ? bc[k * 3 + 1] : s1;
            s2   = better ? bc[k * 3 + 2] : s2;
        }
        if (!__any(wb > 0.0f)) break;

        if (wb > 0.0f) {
            // dense one-level-ish gather: 1 int4 (3 vertex ids) + 12 float4
            const int4 vidx = *reinterpret_cast<const int4*>(faces + (size_t)fsel * 3);
            const float c0 = wb * s0;
            const float c1 = wb * s1;
            const float c2 = wb * s2;
            const float4* r0 = reinterpret_cast<const float4*>(vf + (size_t)vidx.x * 16);
            const float4* r1 = reinterpret_cast<const float4*>(vf + (size_t)vidx.y * 16);
            const float4* r2 = reinterpret_cast<const float4*>(vf + (size_t)vidx.z * 16);
            FMA4(acc0, c0, r0, 0); FMA4(acc1, c0, r0, 1);
            FMA4(acc2, c0, r0, 2); FMA4(acc3, c0, r0, 3);
            FMA4(acc0, c1, r1, 0); FMA4(acc1, c1, r1, 1);
            FMA4(acc2, c1, r1, 2); FMA4(acc3, c1, r1, 3);
            FMA4(acc0, c2, r2, 0); FMA4(acc1, c2, r2, 1);
            FMA4(acc2, c2, r2, 2); FMA4(acc3, c2, r2, 3);
        }

        // clear the consumed slot (static indices only)
#pragma unroll
        for (int k = 0; k < 8; ++k)
            wv[k] = (ksel == k) ? 0.0f : wv[k];
    }

    // ---- epilogue: divide by denom, store channel-major ----
    const float invden = 1.0f / denom;
    const int n  = p >> 16;           // p / HW (HW = 65536)
    const int hw = p & (HW - 1);
    float* o = out + (size_t)n * 17 * HW + hw;
    o[(size_t)0  * HW] = acc0.x * invden;
    o[(size_t)1  * HW] = acc0.y * invden;
    o[(size_t)2  * HW] = acc0.z * invden;
    o[(size_t)3  * HW] = acc0.w * invden;
    o[(size_t)4  * HW] = acc1.x * invden;
    o[(size_t)5  * HW] = acc1.y * invden;
    o[(size_t)6  * HW] = acc1.z * invden;
    o[(size_t)7  * HW] = acc1.w * invden;
    o[(size_t)8  * HW] = acc2.x * invden;
    o[(size_t)9  * HW] = acc2.y * invden;
    o[(size_t)10 * HW] = acc2.z * invden;
    o[(size_t)11 * HW] = acc2.w * invden;
    o[(size_t)12 * HW] = acc3.x * invden;
    o[(size_t)13 * HW] = acc3.y * invden;
    o[(size_t)14 * HW] = acc3.z * invden;
    o[(size_t)15 * HW] = acc3.w * invden;
    o[(size_t)16 * HW] = 1.0f - keep;   // alpha
}

extern "C" void kernel_launch(void* const* d_in, const int* in_sizes, int n_in,
                              void* d_out, int out_size, void* d_ws, size_t ws_size,
                              hipStream_t stream) {
    const float* vf    = (const float*)d_in[0];
    const float* bary  = (const float*)d_in[1];
    const float* dists = (const float*)d_in[2];
    const float* zbuf  = (const float*)d_in[3];
    const int*   faces = (const int*)d_in[4];
    const int*   p2f   = (const int*)d_in[5];
    float* out = (float*)d_out;

    render_kernel<<<dim3(P / 256), dim3(256), 0, stream>>>(
        vf, bary, dists, zbuf, faces, p2f, out);
}

// Round 6
// 21.175 us; speedup vs baseline: 1.4552x; 1.1184x over previous
//
#include <hip/hip_runtime.h>
#include <math.h>

namespace {
constexpr int Nn = 4, Hh = 256, Ww = 256;
constexpr int HW = Hh * Ww;
constexpr int P  = Nn * HW;          // 262144 pixels
constexpr float ZFAR  = 100.0f;
constexpr float ZNEAR = 1.0f;
constexpr float INV_SIG = 1.0f / (1e-4f + 1e-8f);   // 1/(SIGMA+1e-8)
constexpr float INV_GAM = 1e4f;                     // 1/GAMMA
constexpr float EPSF    = 1e-10f;
constexpr float INV_ZR  = 1.0f / (ZFAR - ZNEAR);
}

// quad broadcast via DPP quad_perm (VALU pipe, compile-time ctrl)
#define QB_I(v, S) __builtin_amdgcn_mov_dpp((v), ((S) * 0x55), 0xf, 0xf, true)
#define QB_F(v, S) __int_as_float(QB_I(__float_as_int(v), S))

// slot S: broadcast owner (lane qb+S)'s selection to the quad; each lane loads
// its 16B chunk of the 3 vertex rows (quad -> same 64B line -> 1 line-request)
#define DO_SLOT(S, PS)                                                         \
    {                                                                          \
        const float ws = QB_F(wb, S);                                          \
        if (ws > 0.0f) {                                                       \
            const int   g0 = QB_I(vx, S);                                      \
            const int   g1 = QB_I(vy, S);                                      \
            const int   g2 = QB_I(vz, S);                                      \
            const float w0 = QB_F(c0, S);                                      \
            const float w1 = QB_F(c1, S);                                      \
            const float w2 = QB_F(c2, S);                                      \
            const float4 r0 = *(reinterpret_cast<const float4*>(vf + (size_t)g0 * 16) + cq); \
            const float4 r1 = *(reinterpret_cast<const float4*>(vf + (size_t)g1 * 16) + cq); \
            const float4 r2 = *(reinterpret_cast<const float4*>(vf + (size_t)g2 * 16) + cq); \
            PS.x = fmaf(w0, r0.x, fmaf(w1, r1.x, fmaf(w2, r2.x, PS.x)));       \
            PS.y = fmaf(w0, r0.y, fmaf(w1, r1.y, fmaf(w2, r2.y, PS.y)));       \
            PS.z = fmaf(w0, r0.z, fmaf(w1, r1.z, fmaf(w2, r2.z, PS.z)));       \
            PS.w = fmaf(w0, r0.w, fmaf(w1, r1.w, fmaf(w2, r2.w, PS.w)));       \
        }                                                                      \
    }

__global__ __launch_bounds__(256) void render_kernel(
    const float* __restrict__ vf,     // (V,16)
    const float* __restrict__ bary,   // (P,8,3)
    const float* __restrict__ dists,  // (P,8)
    const float* __restrict__ zbuf,   // (P,8)
    const int*  __restrict__ faces,   // (F,3)
    const int*  __restrict__ p2f,     // (P,8)
    float* __restrict__ out)          // (N,17,H,W)
{
    __shared__ float xp[256 * 20];    // 80B/pixel transpose scratch (bank-clean)
    const int pp = threadIdx.x;
    const int p  = blockIdx.x * 256 + pp;
    const int cq = pp & 3;            // chunk role within quad
    const int qb = pp & ~3;           // quad base (pixel-local)

    // ---- streaming loads (p2f, zbuf, dists) ----
    const int4*   fp = reinterpret_cast<const int4*>(p2f + (size_t)p * 8);
    const float4* zp = reinterpret_cast<const float4*>(zbuf + (size_t)p * 8);
    const float4* dp = reinterpret_cast<const float4*>(dists + (size_t)p * 8);
    int4   fA = fp[0], fB = fp[1];
    float4 zA = zp[0], zB = zp[1];
    float4 dA = dp[0], dB = dp[1];

    int fk[8] = {fA.x, fA.y, fA.z, fA.w, fB.x, fB.y, fB.z, fB.w};
    float zraw[8] = {zA.x, zA.y, zA.z, zA.w, zB.x, zB.y, zB.z, zB.w};
    float dk[8] = {dA.x, dA.y, dA.z, dA.w, dB.x, dB.y, dB.z, dB.w};

    // ---- pass 1: z_inv and max ----
    float zi[8];
    float zmax = EPSF;
#pragma unroll
    for (int k = 0; k < 8; ++k) {
        const bool valid = fk[k] >= 0;
        float zv = valid ? (ZFAR - zraw[k]) * INV_ZR : 0.0f;
        zi[k] = zv;
        zmax = fmaxf(zmax, zv);
    }

    // ---- pass 2: weights, denom, alpha ----
    const float delta = fmaxf(__expf((EPSF - zmax) * INV_GAM), EPSF);
    float denom = delta;
    float keep  = 1.0f;
    float wv[8];
#pragma unroll
    for (int k = 0; k < 8; ++k) {
        const bool valid = fk[k] >= 0;
        float pr = valid ? 1.0f / (1.0f + __expf(dk[k] * INV_SIG)) : 0.0f;
        keep *= (1.0f - pr);
        float w = pr * __expf((zi[k] - zmax) * INV_GAM);
        wv[k] = w;
        denom += w;
    }

    // ---- iterative argmax + quad-cooperative gather ----
    float4 ps0 = make_float4(0.f, 0.f, 0.f, 0.f);
    float4 ps1 = make_float4(0.f, 0.f, 0.f, 0.f);
    float4 ps2 = make_float4(0.f, 0.f, 0.f, 0.f);
    float4 ps3 = make_float4(0.f, 0.f, 0.f, 0.f);

    while (true) {
        float wb = 0.0f;
        int fsel = 0, ksel = -1;
#pragma unroll
        for (int k = 0; k < 8; ++k) {
            const bool better = wv[k] > wb;
            wb   = better ? wv[k] : wb;
            fsel = better ? fk[k] : fsel;
            ksel = better ? k : ksel;
        }
        if (!__any(wb > 0.0f)) break;

        // owner loads face ids + lazy bary (zero-init -> speculation-safe)
        int vx = 0, vy = 0, vz = 0;
        float c0 = 0.0f, c1 = 0.0f, c2 = 0.0f;
        if (wb > 0.0f) {
            const int4 vidx = *reinterpret_cast<const int4*>(faces + (size_t)fsel * 3);
            const float4 bq = *reinterpret_cast<const float4*>(bary + (size_t)p * 24 + ksel * 3);
            vx = vidx.x; vy = vidx.y; vz = vidx.z;
            c0 = wb * bq.x; c1 = wb * bq.y; c2 = wb * bq.z;
        }

        DO_SLOT(0, ps0)
        DO_SLOT(1, ps1)
        DO_SLOT(2, ps2)
        DO_SLOT(3, ps3)

        // clear consumed slot (static indices only)
#pragma unroll
        for (int k = 0; k < 8; ++k)
            wv[k] = (k == ksel) ? 0.0f : wv[k];
    }

    // ---- 4x4 quad transpose via LDS: distributed chunks -> per-pixel ----
    *reinterpret_cast<float4*>(&xp[(qb + 0) * 20 + cq * 4]) = ps0;
    *reinterpret_cast<float4*>(&xp[(qb + 1) * 20 + cq * 4]) = ps1;
    *reinterpret_cast<float4*>(&xp[(qb + 2) * 20 + cq * 4]) = ps2;
    *reinterpret_cast<float4*>(&xp[(qb + 3) * 20 + cq * 4]) = ps3;
    __syncthreads();
    const float4 a0 = *reinterpret_cast<const float4*>(&xp[pp * 20 + 0]);
    const float4 a1 = *reinterpret_cast<const float4*>(&xp[pp * 20 + 4]);
    const float4 a2 = *reinterpret_cast<const float4*>(&xp[pp * 20 + 8]);
    const float4 a3 = *reinterpret_cast<const float4*>(&xp[pp * 20 + 12]);

    // ---- epilogue: divide by denom, store channel-major ----
    const float invden = 1.0f / denom;
    const int n  = p >> 16;           // p / HW (HW = 65536)
    const int hw = p & (HW - 1);
    float* o = out + (size_t)n * 17 * HW + hw;
    o[(size_t)0  * HW] = a0.x * invden;
    o[(size_t)1  * HW] = a0.y * invden;
    o[(size_t)2  * HW] = a0.z * invden;
    o[(size_t)3  * HW] = a0.w * invden;
    o[(size_t)4  * HW] = a1.x * invden;
    o[(size_t)5  * HW] = a1.y * invden;
    o[(size_t)6  * HW] = a1.z * invden;
    o[(size_t)7  * HW] = a1.w * invden;
    o[(size_t)8  * HW] = a2.x * invden;
    o[(size_t)9  * HW] = a2.y * invden;
    o[(size_t)10 * HW] = a2.z * invden;
    o[(size_t)11 * HW] = a2.w * invden;
    o[(size_t)12 * HW] = a3.x * invden;
    o[(size_t)13 * HW] = a3.y * invden;
    o[(size_t)14 * HW] = a3.z * invden;
    o[(size_t)15 * HW] = a3.w * invden;
    o[(size_t)16 * HW] = 1.0f - keep;   // alpha
}

extern "C" void kernel_launch(void* const* d_in, const int* in_sizes, int n_in,
                              void* d_out, int out_size, void* d_ws, size_t ws_size,
                              hipStream_t stream) {
    const float* vf    = (const float*)d_in[0];
    const float* bary  = (const float*)d_in[1];
    const float* dists = (const float*)d_in[2];
    const float* zbuf  = (const float*)d_in[3];
    const int*   faces = (const int*)d_in[4];
    const int*   p2f   = (const int*)d_in[5];
    float* out = (float*)d_out;

    render_kernel<<<dim3(P / 256), dim3(256), 0, stream>>>(
        vf, bary, dists, zbuf, faces, p2f, out);
}